// Round 3
// baseline (897.969 us; speedup 1.0000x reference)
//
#include <hip/hip_runtime.h>
#include <hip/hip_bf16.h>
#include <math.h>

// All inputs and the output are FLOAT32 (reference dtype). The "bf16" in the
// harness label is a literal string, not a dtype indicator. R2/R3 passed via
// the runtime-detector's fp32 path; hard-coding bf16 (R4/R6) produced NaN.
//
// R1 lesson: k_upconv_quad with acc[4][16] (64 regs) spilled to scratch
// (VGPR_Count=68 < accumulator footprint; VALUBusy 1.3%) -> 137us on L6.
// Fix: CO_BLK=8 (acc[4][8]=32 regs), float4 weight loads, no launch_bounds.

#define HH 512
#define WWI 512
#define HWP (HH*WWI)

// ---------------- layer 0: 1x1 conv on upsampled 2x2 + leakyrelu + coordconv ----------------
__global__ void k_layer0(const float* __restrict__ xin, const float* __restrict__ w,
                         const float* __restrict__ bias, float* __restrict__ out)
{
  for (int idx = threadIdx.x; idx < 3*66*4; idx += blockDim.x) {
    int pos = idx & 3;
    int c = (idx >> 2) % 66;
    int b = idx / (66*4);
    float v;
    if (c < 64) {
      float a = bias[c];
      #pragma unroll
      for (int ci = 0; ci < 3; ci++) a += w[c*3+ci] * xin[b*3+ci];
      v = (a >= 0.f) ? a : 0.01f*a;
    } else {
      int xx = pos & 1, yy = pos >> 1;
      v = (c == 64) ? 2.f*(float)xx : 2.f*(float)yy;
    }
    out[idx] = v;
  }
}

__device__ __forceinline__ int refl_up(int t, int n) {
  t = (t < 0) ? -t : t;
  t = (t >= n) ? (2*(n-1) - t) : t;
  return t >> 1;
}

// ---------------- LDS conv: upsample x2 + reflect-pad + 3x3 + leakyrelu ----------------
template<int G>
__global__ void k_conv_lds(const float* __restrict__ in, float* __restrict__ out,
                           const float* __restrict__ w, const float* __restrict__ bias,
                           int B, int Cin, int CO, int COB, int Hin, int TR, int SPAN)
{
  extern __shared__ float lds[];
  const int Hout = Hin * 2;
  const int rowTiles = Hout / TR;
  const int coTiles = CO / COB;
  int bid = blockIdx.x;
  int tile = bid % rowTiles;
  int cot  = (bid / rowTiles) % coTiles;
  int b    = bid / (rowTiles * coTiles);
  int tr0  = tile * TR;
  int co_base = cot * COB;

  int r0 = tr0/2 - 1;
  if (r0 < 0) r0 = 0;
  if (r0 > Hin - SPAN) r0 = Hin - SPAN;

  float* wlds = lds;                    // COB*Cin*9
  float* blds = wlds + COB*Cin*9;       // COB
  float* ilds = blds + COB;             // Cin*SPAN*Hin

  int nt = blockDim.x, tid = threadIdx.x;

  const float* wsrc = w + (size_t)co_base*Cin*9;
  for (int i = tid; i < COB*Cin*9; i += nt) wlds[i] = wsrc[i];
  for (int i = tid; i < COB; i += nt) blds[i] = bias[co_base + i];
  int icount = Cin*SPAN*Hin;
  for (int i = tid; i < icount; i += nt) {
    int col = i % Hin;
    int r = (i / Hin) % SPAN;
    int ci = i / (Hin*SPAN);
    ilds[i] = in[(((size_t)b*Cin + ci)*Hin + (r0 + r))*Hin + col];
  }
  __syncthreads();

  int npix = TR * Hout;
  int ngr = COB / G;
  int items = ngr * npix;
  for (int it = tid; it < items; it += nt) {
    int pix = it % npix;
    int cg = it / npix;
    int x = pix % Hout;
    int y = tr0 + pix / Hout;

    int ry[3], rx[3];
    #pragma unroll
    for (int d = 0; d < 3; d++) {
      int s = refl_up(y - 1 + d, Hout) - r0;
      s = (s < 0) ? 0 : s;
      s = (s > SPAN-1) ? SPAN-1 : s;
      ry[d] = s;
      rx[d] = refl_up(x - 1 + d, Hout);
    }

    float acc[G];
    #pragma unroll
    for (int j = 0; j < G; j++) acc[j] = blds[cg*G + j];

    for (int ci = 0; ci < Cin; ci++) {
      const float* ib = ilds + (size_t)ci*SPAN*Hin;
      float p[9];
      #pragma unroll
      for (int dy = 0; dy < 3; dy++)
        #pragma unroll
        for (int dx = 0; dx < 3; dx++)
          p[dy*3+dx] = ib[ry[dy]*Hin + rx[dx]];
      const float* wc = wlds + ((size_t)(cg*G)*Cin + ci)*9;
      #pragma unroll
      for (int j = 0; j < G; j++) {
        #pragma unroll
        for (int k = 0; k < 9; k++) acc[j] += wc[(size_t)j*Cin*9 + k] * p[k];
      }
    }

    #pragma unroll
    for (int j = 0; j < G; j++) {
      float v = acc[j];
      v = (v >= 0.f) ? v : 0.01f*v;
      out[(((size_t)b*CO + co_base + cg*G + j)*Hout + y)*Hout + x] = v;
    }
  }
}

// ---------------- weight folding for upsample-conv quad decomposition ----------------
// upsample x2 + reflect-pad + 3x3 VALID conv == per-output-parity 2x2 conv on the
// ORIGINAL (pre-upsample) image. Folded layout (float4-friendly):
//   f[((co*Cin + ci)*16) + p*4 + ky*2 + kx], p = py*2+px.
__global__ void k_foldw3(const float* __restrict__ w6, const float* __restrict__ w7,
                         const float* __restrict__ w8, float* __restrict__ f6,
                         float* __restrict__ f7, float* __restrict__ f8)
{
  int idx = blockIdx.x*blockDim.x + threadIdx.x;
  const float* w; float* f; int n;
  if (idx < 512)       { w = w6; f = f6; n = idx; }        // CO=16, Cin=32
  else if (idx < 768)  { w = w7; f = f7; n = idx - 512; }  // CO=16, Cin=16
  else if (idx < 1024) { w = w8; f = f8; n = idx - 768; }  // CO=16, Cin=16
  else return;

  const float* ws = w + (size_t)n*9;
  float W[9];
  #pragma unroll
  for (int k = 0; k < 9; k++) W[k] = ws[k];

  // row folds a[py][ky][c]
  float a[2][2][3];
  #pragma unroll
  for (int c = 0; c < 3; c++) {
    a[0][0][c] = W[c];          a[0][1][c] = W[3+c] + W[6+c];
    a[1][0][c] = W[c] + W[3+c]; a[1][1][c] = W[6+c];
  }
  float* fo = f + (size_t)n*16;
  #pragma unroll
  for (int py = 0; py < 2; py++)
    #pragma unroll
    for (int px = 0; px < 2; px++) {
      int p = py*2 + px;
      #pragma unroll
      for (int ky = 0; ky < 2; ky++) {
        float kx0 = (px == 0) ? a[py][ky][0] : (a[py][ky][0] + a[py][ky][1]);
        float kx1 = (px == 0) ? (a[py][ky][1] + a[py][ky][2]) : a[py][ky][2];
        fo[p*4 + ky*2 + 0] = kx0;
        fo[p*4 + ky*2 + 1] = kx1;
      }
    }
}

// ---------------- quad upconv, co-split: one thread = 2x2 output quad x COB channels ----------
// acc[4][COB] stays in registers (COB=8 -> 32 regs). float4 weight loads (1 per 4 FMAs).
// cb is the SLOW grid axis so pixel loads / float2 stores stay coalesced in X.
template<int COB>
__global__ void k_upconv_q(const float* __restrict__ in, float* __restrict__ out,
                           const float* __restrict__ wfold, const float* __restrict__ bias,
                           int B, int Cin, int CO, int Hin)
{
  int total = B * Hin * Hin;
  int nitems = total * (CO / COB);
  int idx = blockIdx.x*blockDim.x + threadIdx.x;
  if (idx >= nitems) return;
  int cb = idx / total;
  int r  = idx % total;
  int Hout = Hin * 2;
  int X = r % Hin;
  int Y = (r / Hin) % Hin;
  int b = r / (Hin * Hin);
  int co0 = cb * COB;

  // source rows/cols of the 3x3 patch (reflection == clamp at borders)
  int R0 = (Y == 0) ? 0 : Y-1;
  int R2 = (Y == Hin-1) ? Hin-1 : Y+1;
  int C0 = (X == 0) ? 0 : X-1;
  int C2 = (X == Hin-1) ? Hin-1 : X+1;

  float acc0[COB], acc1[COB], acc2[COB], acc3[COB];
  #pragma unroll
  for (int j = 0; j < COB; j++) {
    float bv = bias[co0 + j];
    acc0[j] = bv; acc1[j] = bv; acc2[j] = bv; acc3[j] = bv;
  }

  const size_t plane = (size_t)Hin * Hin;
  const float* ibase = in + (size_t)b * Cin * plane;
  for (int ci = 0; ci < Cin; ci++) {
    const float* ip = ibase + (size_t)ci * plane;
    const float* r0 = ip + (size_t)R0 * Hin;
    const float* r1 = ip + (size_t)Y  * Hin;
    const float* r2 = ip + (size_t)R2 * Hin;
    float p00 = r0[C0], p01 = r0[X], p02 = r0[C2];
    float p10 = r1[C0], p11 = r1[X], p12 = r1[C2];
    float p20 = r2[C0], p21 = r2[X], p22 = r2[C2];

    const float* wc = wfold + ((size_t)co0 * Cin + ci) * 16;
    #pragma unroll
    for (int j = 0; j < COB; j++) {
      const float4* w4 = reinterpret_cast<const float4*>(wc + (size_t)j * Cin * 16);
      float4 w0 = w4[0], w1 = w4[1], w2 = w4[2], w3 = w4[3];
      acc0[j] += w0.x*p00 + w0.y*p01 + w0.z*p10 + w0.w*p11;
      acc1[j] += w1.x*p01 + w1.y*p02 + w1.z*p11 + w1.w*p12;
      acc2[j] += w2.x*p10 + w2.y*p11 + w2.z*p20 + w2.w*p21;
      acc3[j] += w3.x*p11 + w3.y*p12 + w3.z*p21 + w3.w*p22;
    }
  }

  int yo = 2*Y, xo = 2*X;
  size_t oplane = (size_t)Hout * Hout;
  float* obase = out + ((size_t)b * CO + co0) * oplane + (size_t)yo * Hout + xo;
  #pragma unroll
  for (int j = 0; j < COB; j++) {
    float v0 = acc0[j]; v0 = (v0 >= 0.f) ? v0 : 0.01f*v0;
    float v1 = acc1[j]; v1 = (v1 >= 0.f) ? v1 : 0.01f*v1;
    float v2 = acc2[j]; v2 = (v2 >= 0.f) ? v2 : 0.01f*v2;
    float v3 = acc3[j]; v3 = (v3 >= 0.f) ? v3 : 0.01f*v3;
    float* op = obase + (size_t)j * oplane;
    *reinterpret_cast<float2*>(op)        = make_float2(v0, v1);
    *reinterpret_cast<float2*>(op + Hout) = make_float2(v2, v3);
  }
}

// ---------------- thread-per-pixel upconv (R3-proven) for small layers ----------------
template<int CO>
__global__ void k_upconv(const float* __restrict__ in, float* __restrict__ out,
                         const float* __restrict__ w, const float* __restrict__ bias,
                         int B, int Cin, int Hin)
{
  int Hout = Hin * 2;
  int total = B * Hout * Hout;
  int idx = blockIdx.x*blockDim.x + threadIdx.x;
  if (idx >= total) return;
  int x = idx % Hout;
  int y = (idx / Hout) % Hout;
  int b = idx / (Hout * Hout);

  int ry[3], rx[3];
  #pragma unroll
  for (int d = 0; d < 3; d++) {
    ry[d] = refl_up(y - 1 + d, Hout);
    rx[d] = refl_up(x - 1 + d, Hout);
  }

  float acc[CO];
  #pragma unroll
  for (int co = 0; co < CO; co++) acc[co] = bias[co];

  for (int ci = 0; ci < Cin; ci++) {
    const float* ib = in + ((size_t)(b*Cin) + ci) * (Hin*Hin);
    float p[9];
    #pragma unroll
    for (int dy = 0; dy < 3; dy++)
      #pragma unroll
      for (int dx = 0; dx < 3; dx++)
        p[dy*3+dx] = ib[ry[dy]*Hin + rx[dx]];
    const float* wc = w + ci*9;
    #pragma unroll
    for (int co = 0; co < CO; co++) {
      const float* wcc = wc + co*Cin*9;
      #pragma unroll
      for (int k = 0; k < 9; k++) acc[co] += wcc[k] * p[k];
    }
  }

  int pix = y*Hout + x;
  #pragma unroll
  for (int co = 0; co < CO; co++) {
    float v = acc[co];
    v = (v >= 0.f) ? v : 0.01f*v;
    out[((size_t)(b*CO) + co)*(Hout*Hout) + pix] = v;
  }
}

// ---------------- final: reflect-pad + 3x3 conv (16 -> 6) + tanh ----------------
__global__ void k_final(const float* __restrict__ in, float* __restrict__ out,
                        const float* __restrict__ w, const float* __restrict__ bias)
{
  int idx = blockIdx.x*blockDim.x + threadIdx.x;
  int total = 3 * HWP;
  if (idx >= total) return;
  int x = idx & (WWI-1);
  int y = (idx >> 9) & (HH-1);
  int b = idx / HWP;

  int ry[3], rx[3];
  #pragma unroll
  for (int d = 0; d < 3; d++) {
    int t = y - 1 + d;
    t = (t < 0) ? -t : t;
    ry[d] = (t >= HH) ? (2*(HH-1) - t) : t;
    t = x - 1 + d;
    t = (t < 0) ? -t : t;
    rx[d] = (t >= WWI) ? (2*(WWI-1) - t) : t;
  }

  float acc[6];
  #pragma unroll
  for (int co = 0; co < 6; co++) acc[co] = bias[co];

  for (int ci = 0; ci < 16; ci++) {
    const float* ib = in + ((size_t)(b*16) + ci) * HWP;
    float p[9];
    #pragma unroll
    for (int dy = 0; dy < 3; dy++)
      #pragma unroll
      for (int dx = 0; dx < 3; dx++)
        p[dy*3+dx] = ib[ry[dy]*WWI + rx[dx]];
    const float* wc = w + ci*9;
    #pragma unroll
    for (int co = 0; co < 6; co++) {
      const float* wcc = wc + co*16*9;
      #pragma unroll
      for (int k = 0; k < 9; k++) acc[co] += wcc[k] * p[k];
    }
  }

  int pix = y*WWI + x;
  #pragma unroll
  for (int co = 0; co < 6; co++)
    out[((size_t)(b*6) + co)*HWP + pix] = tanhf(acc[co]);
}

// ---------------- blending: fused grid-sample + weighting (all fp32) ----------------
__global__ void k_blend(const float* __restrict__ xin, const float* __restrict__ neighbors,
                        const int* __restrict__ aidx, const float* __restrict__ albedos,
                        const float* __restrict__ flows, float* __restrict__ out)
{
  int idx = blockIdx.x*blockDim.x + threadIdx.x;
  if (idx >= HWP) return;
  int xo = idx & (WWI-1);
  int yo = idx >> 9;

  float xv[9];
  #pragma unroll
  for (int i = 0; i < 9; i++) xv[i] = xin[i];

  float f0[6];
  #pragma unroll
  for (int c = 0; c < 6; c++) f0[c] = flows[(size_t)c*HWP + idx];

  const float* alb = albedos + (size_t)aidx[0]*3*HWP;
  float albp[3];
  #pragma unroll
  for (int ch = 0; ch < 3; ch++) albp[ch] = alb[(size_t)ch*HWP + idx];

  float num0 = 0.f, num1 = 0.f, num2 = 0.f;
  float wsum = 0.f;

  #pragma unroll
  for (int n = 0; n < 2; n++) {
    float dl = xv[0] - xv[(n+1)*3 + 0];
    float dv = xv[1] - xv[(n+1)*3 + 1];
    float dt = xv[2] - xv[(n+1)*3 + 2];
    bool fl = fabsf(dl) > 0.f;

    float ofx = dl*f0[0] + dv*f0[2] + dt*f0[4];
    float ofy = dl*f0[1] + dv*f0[3] + dt*f0[5];

    float gx = ((-1.f + (2.f/511.f)*(float)xo) + ofx + 1.f)*256.f - 0.5f;
    float gy = ((-1.f + (2.f/511.f)*(float)yo) + ofy + 1.f)*256.f - 0.5f;
    gx = fminf(fmaxf(gx, 0.f), 511.f);
    gy = fminf(fmaxf(gy, 0.f), 511.f);

    float x0f = floorf(gx), y0f = floorf(gy);
    float wx = gx - x0f, wy = gy - y0f;
    int x0i = (int)x0f, y0i = (int)y0f;
    int x1i = min(x0i + 1, WWI-1), y1i = min(y0i + 1, HH-1);

    float cw[4] = {(1.f-wx)*(1.f-wy), wx*(1.f-wy), (1.f-wx)*wy, wx*wy};
    int   cp[4] = {y0i*WWI + x0i, y0i*WWI + x1i, y1i*WWI + x0i, y1i*WWI + x1i};

    const float* nb = neighbors + (size_t)n*3*HWP;
    const float* Fn = flows + (size_t)(n+1)*6*HWP;

    float s0=0.f,s1=0.f,s2=0.f;
    float l0=0.f,l1=0.f,v0=0.f,v1=0.f,t0=0.f,t1=0.f;
    #pragma unroll
    for (int c = 0; c < 4; c++) {
      int p = cp[c];
      float ww = cw[c];
      float n0 = nb[p];
      float n1 = nb[HWP + p];
      float n2 = nb[2*HWP + p];
      if (fl) {
        n0 /= alb[p];
        n1 /= alb[HWP + p];
        n2 /= alb[2*HWP + p];
      }
      s0 += ww*n0; s1 += ww*n1; s2 += ww*n2;
      l0 += ww*Fn[p];             l1 += ww*Fn[HWP + p];
      v0 += ww*Fn[2*HWP + p];     v1 += ww*Fn[3*HWP + p];
      t0 += ww*Fn[4*HWP + p];     t1 += ww*Fn[5*HWP + p];
    }

    float wi0 = fl ? s0*albp[0] : s0;
    float wi1 = fl ? s1*albp[1] : s1;
    float wi2 = fl ? s2*albp[2] : s2;

    float obx = dl*l0 + dv*v0 + dt*t0;
    float oby = dl*l1 + dv*v1 + dt*t1;
    float dist = fabsf(ofx - obx) + fabsf(ofy - oby);
    float wgt = expf(-51.2f * dist);

    wsum += wgt;
    num0 += wgt*wi0; num1 += wgt*wi1; num2 += wgt*wi2;
  }

  float inv = 1.f / (wsum + 1e-5f);
  out[idx]         = num0*inv;
  out[HWP + idx]   = num1*inv;
  out[2*HWP + idx] = num2*inv;
}

// ---------------- launch ----------------
extern "C" void kernel_launch(void* const* d_in, const int* in_sizes, int n_in,
                              void* d_out, int out_size, void* d_ws, size_t ws_size,
                              hipStream_t stream) {
  const float* x         = (const float*)d_in[0];
  const float* neighbors = (const float*)d_in[1];
  const int*   aidx      = (const int*)d_in[2];
  const float* wts[10];
  const float* bis[10];
  for (int i = 0; i < 9; i++) { wts[i] = (const float*)d_in[3+2*i]; bis[i] = (const float*)d_in[4+2*i]; }
  wts[9] = (const float*)d_in[21];   // wf
  bis[9] = (const float*)d_in[22];   // bf
  const float* albedos = (const float*)d_in[23];

  float* wk   = (float*)d_ws;
  float* bufS = wk;                   // 792 floats (layer0 out)
  float* bufA = wk + 800;             // up to 4,718,592 floats
  float* bufB = bufA + 4718592;       // up to 12,582,912 floats
  size_t need = (size_t)(800 + 4718592 + 12582912) * 4;
  if (ws_size < need) return;

  // Folded-weight buffers live in bufA slack [3,200,000, 3,216,384):
  // above L7's peak use (3,145,728 floats) and only overwritten by k_final
  // (4,718,592 floats) AFTER L8 has consumed them. No workspace growth.
  float* wf6 = bufA + 3200000;            // 16*32*16 = 8192 floats
  float* wf7 = wf6 + 8192;                // 16*16*16 = 4096 floats
  float* wf8 = wf7 + 4096;                // 16*16*16 = 4096 floats
  k_foldw3<<<4, 256, 0, stream>>>(wts[6], wts[7], wts[8], wf6, wf7, wf8);

  k_layer0<<<1, 256, 0, stream>>>(x, wts[0], bis[0], bufS);

  auto spanOf = [](int Hin, int TR) { int s = TR/2 + 2; return (s > Hin) ? Hin : s; };
  auto ldsB = [&](int COB, int Cin, int Hin, int TR) {
    return (size_t)(COB*Cin*9 + COB + Cin*spanOf(Hin,TR)*Hin) * 4;
  };

  // L1: Cin=66 CO=64 Hin=2  | COB=16 TR=4 G=1 | blocks 3*4*1=12
  k_conv_lds<1><<<12, 256, ldsB(16,66,2,4), stream>>>(bufS, bufA, wts[1], bis[1],
                                                      3, 66, 64, 16, 2, 4, spanOf(2,4));
  // L2: Cin=64 CO=64 Hin=4  | COB=8 TR=8 G=1 | blocks 3*8*1=24
  k_conv_lds<1><<<24, 256, ldsB(8,64,4,8), stream>>>(bufA, bufB, wts[2], bis[2],
                                                     3, 64, 64, 8, 4, 8, spanOf(4,8));
  // L3: Cin=64 CO=32 Hin=8  | COB=4 TR=16 G=2 | blocks 3*8*1=24
  k_conv_lds<2><<<24, 256, ldsB(4,64,8,16), stream>>>(bufB, bufA, wts[3], bis[3],
                                                      3, 64, 32, 4, 8, 16, spanOf(8,16));
  // L4: Cin=32 CO=32 Hin=16 | COB=8 TR=8 G=2 | blocks 3*4*4=48
  k_conv_lds<2><<<48, 256, ldsB(8,32,16,8), stream>>>(bufA, bufB, wts[4], bis[4],
                                                      3, 32, 32, 8, 16, 8, spanOf(16,8));
  // L5: Cin=32 CO=32 Hin=32 | COB=8 TR=8 G=4 | blocks 3*4*8=96
  k_conv_lds<4><<<96, 256, ldsB(8,32,32,8), stream>>>(bufB, bufA, wts[5], bis[5],
                                                      3, 32, 32, 8, 32, 8, spanOf(32,8));

  auto blocks = [](int total){ return (total + 255) / 256; };
  // L6: small grid -> proven thread-per-output kernel (quad spilled here in R1)
  k_upconv<16><<<blocks(3*128*128), 256, 0, stream>>>(bufA, bufB, wts[6], bis[6], 3, 32, 64);
  // L7/L8: quad decomposition, co-split x2 (acc[4][8]=32 regs, float4 weights)
  k_upconv_q<8><<<blocks(3*128*128*2), 256, 0, stream>>>(bufB, bufA, wf7, bis[7], 3, 16, 16, 128);
  k_upconv_q<8><<<blocks(3*256*256*2), 256, 0, stream>>>(bufA, bufB, wf8, bis[8], 3, 16, 16, 256);

  k_final<<<blocks(3*HWP), 256, 0, stream>>>(bufB, bufA, wts[9], bis[9]);
  k_blend<<<blocks(HWP), 256, 0, stream>>>(x, neighbors, aidx, albedos, bufA, (float*)d_out);
}

// Round 4
// 636.994 us; speedup vs baseline: 1.4097x; 1.4097x over previous
//
#include <hip/hip_runtime.h>
#include <hip/hip_bf16.h>
#include <math.h>

// All inputs and the output are FLOAT32 (reference dtype). The "bf16" in the
// harness label is a literal string, not a dtype indicator.
//
// R1/R3 lesson: quad upconv spilled twice; VGPR_Count pinned at 64-68 while the
// live set (acc + 9 pixels + 16 weights + addr) needs ~75-90 -> scratch traffic
// (R3: 747 MB HBM/dispatch, VALUBusy 9.4%). Root cause: allocator VGPR cap, not
// the array indexing. Fix: __launch_bounds__(256,4) -> cap 128 VGPR, plus COB=4.

#define HH 512
#define WWI 512
#define HWP (HH*WWI)

// ---------------- layer 0: 1x1 conv on upsampled 2x2 + leakyrelu + coordconv ----------------
__global__ void k_layer0(const float* __restrict__ xin, const float* __restrict__ w,
                         const float* __restrict__ bias, float* __restrict__ out)
{
  for (int idx = threadIdx.x; idx < 3*66*4; idx += blockDim.x) {
    int pos = idx & 3;
    int c = (idx >> 2) % 66;
    int b = idx / (66*4);
    float v;
    if (c < 64) {
      float a = bias[c];
      #pragma unroll
      for (int ci = 0; ci < 3; ci++) a += w[c*3+ci] * xin[b*3+ci];
      v = (a >= 0.f) ? a : 0.01f*a;
    } else {
      int xx = pos & 1, yy = pos >> 1;
      v = (c == 64) ? 2.f*(float)xx : 2.f*(float)yy;
    }
    out[idx] = v;
  }
}

__device__ __forceinline__ int refl_up(int t, int n) {
  t = (t < 0) ? -t : t;
  t = (t >= n) ? (2*(n-1) - t) : t;
  return t >> 1;
}

// ---------------- LDS conv: upsample x2 + reflect-pad + 3x3 + leakyrelu ----------------
template<int G>
__global__ void k_conv_lds(const float* __restrict__ in, float* __restrict__ out,
                           const float* __restrict__ w, const float* __restrict__ bias,
                           int B, int Cin, int CO, int COB, int Hin, int TR, int SPAN)
{
  extern __shared__ float lds[];
  const int Hout = Hin * 2;
  const int rowTiles = Hout / TR;
  const int coTiles = CO / COB;
  int bid = blockIdx.x;
  int tile = bid % rowTiles;
  int cot  = (bid / rowTiles) % coTiles;
  int b    = bid / (rowTiles * coTiles);
  int tr0  = tile * TR;
  int co_base = cot * COB;

  int r0 = tr0/2 - 1;
  if (r0 < 0) r0 = 0;
  if (r0 > Hin - SPAN) r0 = Hin - SPAN;

  float* wlds = lds;                    // COB*Cin*9
  float* blds = wlds + COB*Cin*9;       // COB
  float* ilds = blds + COB;             // Cin*SPAN*Hin

  int nt = blockDim.x, tid = threadIdx.x;

  const float* wsrc = w + (size_t)co_base*Cin*9;
  for (int i = tid; i < COB*Cin*9; i += nt) wlds[i] = wsrc[i];
  for (int i = tid; i < COB; i += nt) blds[i] = bias[co_base + i];
  int icount = Cin*SPAN*Hin;
  for (int i = tid; i < icount; i += nt) {
    int col = i % Hin;
    int r = (i / Hin) % SPAN;
    int ci = i / (Hin*SPAN);
    ilds[i] = in[(((size_t)b*Cin + ci)*Hin + (r0 + r))*Hin + col];
  }
  __syncthreads();

  int npix = TR * Hout;
  int ngr = COB / G;
  int items = ngr * npix;
  for (int it = tid; it < items; it += nt) {
    int pix = it % npix;
    int cg = it / npix;
    int x = pix % Hout;
    int y = tr0 + pix / Hout;

    int ry[3], rx[3];
    #pragma unroll
    for (int d = 0; d < 3; d++) {
      int s = refl_up(y - 1 + d, Hout) - r0;
      s = (s < 0) ? 0 : s;
      s = (s > SPAN-1) ? SPAN-1 : s;
      ry[d] = s;
      rx[d] = refl_up(x - 1 + d, Hout);
    }

    float acc[G];
    #pragma unroll
    for (int j = 0; j < G; j++) acc[j] = blds[cg*G + j];

    for (int ci = 0; ci < Cin; ci++) {
      const float* ib = ilds + (size_t)ci*SPAN*Hin;
      float p[9];
      #pragma unroll
      for (int dy = 0; dy < 3; dy++)
        #pragma unroll
        for (int dx = 0; dx < 3; dx++)
          p[dy*3+dx] = ib[ry[dy]*Hin + rx[dx]];
      const float* wc = wlds + ((size_t)(cg*G)*Cin + ci)*9;
      #pragma unroll
      for (int j = 0; j < G; j++) {
        #pragma unroll
        for (int k = 0; k < 9; k++) acc[j] += wc[(size_t)j*Cin*9 + k] * p[k];
      }
    }

    #pragma unroll
    for (int j = 0; j < G; j++) {
      float v = acc[j];
      v = (v >= 0.f) ? v : 0.01f*v;
      out[(((size_t)b*CO + co_base + cg*G + j)*Hout + y)*Hout + x] = v;
    }
  }
}

// ---------------- weight folding for upsample-conv quad decomposition ----------------
// upsample x2 + reflect-pad + 3x3 VALID conv == per-output-parity 2x2 conv on the
// ORIGINAL (pre-upsample) image. Folded layout (float4-friendly):
//   f[((co*Cin + ci)*16) + p*4 + ky*2 + kx], p = py*2+px.
__global__ void k_foldw3(const float* __restrict__ w6, const float* __restrict__ w7,
                         const float* __restrict__ w8, float* __restrict__ f6,
                         float* __restrict__ f7, float* __restrict__ f8)
{
  int idx = blockIdx.x*blockDim.x + threadIdx.x;
  const float* w; float* f; int n;
  if (idx < 512)       { w = w6; f = f6; n = idx; }        // CO=16, Cin=32
  else if (idx < 768)  { w = w7; f = f7; n = idx - 512; }  // CO=16, Cin=16
  else if (idx < 1024) { w = w8; f = f8; n = idx - 768; }  // CO=16, Cin=16
  else return;

  const float* ws = w + (size_t)n*9;
  float W[9];
  #pragma unroll
  for (int k = 0; k < 9; k++) W[k] = ws[k];

  // row folds a[py][ky][c]
  float a[2][2][3];
  #pragma unroll
  for (int c = 0; c < 3; c++) {
    a[0][0][c] = W[c];          a[0][1][c] = W[3+c] + W[6+c];
    a[1][0][c] = W[c] + W[3+c]; a[1][1][c] = W[6+c];
  }
  float* fo = f + (size_t)n*16;
  #pragma unroll
  for (int py = 0; py < 2; py++)
    #pragma unroll
    for (int px = 0; px < 2; px++) {
      int p = py*2 + px;
      #pragma unroll
      for (int ky = 0; ky < 2; ky++) {
        float kx0 = (px == 0) ? a[py][ky][0] : (a[py][ky][0] + a[py][ky][1]);
        float kx1 = (px == 0) ? (a[py][ky][1] + a[py][ky][2]) : a[py][ky][2];
        fo[p*4 + ky*2 + 0] = kx0;
        fo[p*4 + ky*2 + 1] = kx1;
      }
    }
}

// ---------------- quad upconv, co-split: one thread = 2x2 output quad x COB channels ----------
// acc stays in registers (COB=4 -> 16 regs). float4 weight loads (1 per 4 FMAs).
// __launch_bounds__(256,4): VGPR cap 128 (R1/R3 spilled at the default ~64 cap).
// cb is the SLOW grid axis so pixel loads / float2 stores stay coalesced in X.
template<int COB>
__global__ __launch_bounds__(256, 4)
void k_upconv_q(const float* __restrict__ in, float* __restrict__ out,
                const float* __restrict__ wfold, const float* __restrict__ bias,
                int B, int Cin, int CO, int Hin)
{
  int total = B * Hin * Hin;
  int nitems = total * (CO / COB);
  int idx = blockIdx.x*blockDim.x + threadIdx.x;
  if (idx >= nitems) return;
  int cb = idx / total;
  int r  = idx % total;
  int Hout = Hin * 2;
  int X = r % Hin;
  int Y = (r / Hin) % Hin;
  int b = r / (Hin * Hin);
  int co0 = cb * COB;

  // source rows/cols of the 3x3 patch (reflection == clamp at borders)
  int R0 = (Y == 0) ? 0 : Y-1;
  int R2 = (Y == Hin-1) ? Hin-1 : Y+1;
  int C0 = (X == 0) ? 0 : X-1;
  int C2 = (X == Hin-1) ? Hin-1 : X+1;

  float acc0[COB], acc1[COB], acc2[COB], acc3[COB];
  #pragma unroll
  for (int j = 0; j < COB; j++) {
    float bv = bias[co0 + j];
    acc0[j] = bv; acc1[j] = bv; acc2[j] = bv; acc3[j] = bv;
  }

  const size_t plane = (size_t)Hin * Hin;
  const float* ibase = in + (size_t)b * Cin * plane;
  for (int ci = 0; ci < Cin; ci++) {
    const float* ip = ibase + (size_t)ci * plane;
    const float* r0 = ip + (size_t)R0 * Hin;
    const float* r1 = ip + (size_t)Y  * Hin;
    const float* r2 = ip + (size_t)R2 * Hin;
    float p00 = r0[C0], p01 = r0[X], p02 = r0[C2];
    float p10 = r1[C0], p11 = r1[X], p12 = r1[C2];
    float p20 = r2[C0], p21 = r2[X], p22 = r2[C2];

    const float* wc = wfold + ((size_t)co0 * Cin + ci) * 16;
    #pragma unroll
    for (int j = 0; j < COB; j++) {
      const float4* w4 = reinterpret_cast<const float4*>(wc + (size_t)j * Cin * 16);
      float4 w0 = w4[0], w1 = w4[1], w2 = w4[2], w3 = w4[3];
      acc0[j] += w0.x*p00 + w0.y*p01 + w0.z*p10 + w0.w*p11;
      acc1[j] += w1.x*p01 + w1.y*p02 + w1.z*p11 + w1.w*p12;
      acc2[j] += w2.x*p10 + w2.y*p11 + w2.z*p20 + w2.w*p21;
      acc3[j] += w3.x*p11 + w3.y*p12 + w3.z*p21 + w3.w*p22;
    }
  }

  int yo = 2*Y, xo = 2*X;
  size_t oplane = (size_t)Hout * Hout;
  float* obase = out + ((size_t)b * CO + co0) * oplane + (size_t)yo * Hout + xo;
  #pragma unroll
  for (int j = 0; j < COB; j++) {
    float v0 = acc0[j]; v0 = (v0 >= 0.f) ? v0 : 0.01f*v0;
    float v1 = acc1[j]; v1 = (v1 >= 0.f) ? v1 : 0.01f*v1;
    float v2 = acc2[j]; v2 = (v2 >= 0.f) ? v2 : 0.01f*v2;
    float v3 = acc3[j]; v3 = (v3 >= 0.f) ? v3 : 0.01f*v3;
    float* op = obase + (size_t)j * oplane;
    *reinterpret_cast<float2*>(op)        = make_float2(v0, v1);
    *reinterpret_cast<float2*>(op + Hout) = make_float2(v2, v3);
  }
}

// ---------------- thread-per-pixel upconv (proven) for small layers ----------------
template<int CO>
__global__ void k_upconv(const float* __restrict__ in, float* __restrict__ out,
                         const float* __restrict__ w, const float* __restrict__ bias,
                         int B, int Cin, int Hin)
{
  int Hout = Hin * 2;
  int total = B * Hout * Hout;
  int idx = blockIdx.x*blockDim.x + threadIdx.x;
  if (idx >= total) return;
  int x = idx % Hout;
  int y = (idx / Hout) % Hout;
  int b = idx / (Hout * Hout);

  int ry[3], rx[3];
  #pragma unroll
  for (int d = 0; d < 3; d++) {
    ry[d] = refl_up(y - 1 + d, Hout);
    rx[d] = refl_up(x - 1 + d, Hout);
  }

  float acc[CO];
  #pragma unroll
  for (int co = 0; co < CO; co++) acc[co] = bias[co];

  for (int ci = 0; ci < Cin; ci++) {
    const float* ib = in + ((size_t)(b*Cin) + ci) * (Hin*Hin);
    float p[9];
    #pragma unroll
    for (int dy = 0; dy < 3; dy++)
      #pragma unroll
      for (int dx = 0; dx < 3; dx++)
        p[dy*3+dx] = ib[ry[dy]*Hin + rx[dx]];
    const float* wc = w + ci*9;
    #pragma unroll
    for (int co = 0; co < CO; co++) {
      const float* wcc = wc + co*Cin*9;
      #pragma unroll
      for (int k = 0; k < 9; k++) acc[co] += wcc[k] * p[k];
    }
  }

  int pix = y*Hout + x;
  #pragma unroll
  for (int co = 0; co < CO; co++) {
    float v = acc[co];
    v = (v >= 0.f) ? v : 0.01f*v;
    out[((size_t)(b*CO) + co)*(Hout*Hout) + pix] = v;
  }
}

// ---------------- final: reflect-pad + 3x3 conv (16 -> 6) + tanh ----------------
__global__ void k_final(const float* __restrict__ in, float* __restrict__ out,
                        const float* __restrict__ w, const float* __restrict__ bias)
{
  int idx = blockIdx.x*blockDim.x + threadIdx.x;
  int total = 3 * HWP;
  if (idx >= total) return;
  int x = idx & (WWI-1);
  int y = (idx >> 9) & (HH-1);
  int b = idx / HWP;

  int ry[3], rx[3];
  #pragma unroll
  for (int d = 0; d < 3; d++) {
    int t = y - 1 + d;
    t = (t < 0) ? -t : t;
    ry[d] = (t >= HH) ? (2*(HH-1) - t) : t;
    t = x - 1 + d;
    t = (t < 0) ? -t : t;
    rx[d] = (t >= WWI) ? (2*(WWI-1) - t) : t;
  }

  float acc[6];
  #pragma unroll
  for (int co = 0; co < 6; co++) acc[co] = bias[co];

  for (int ci = 0; ci < 16; ci++) {
    const float* ib = in + ((size_t)(b*16) + ci) * HWP;
    float p[9];
    #pragma unroll
    for (int dy = 0; dy < 3; dy++)
      #pragma unroll
      for (int dx = 0; dx < 3; dx++)
        p[dy*3+dx] = ib[ry[dy]*WWI + rx[dx]];
    const float* wc = w + ci*9;
    #pragma unroll
    for (int co = 0; co < 6; co++) {
      const float* wcc = wc + co*16*9;
      #pragma unroll
      for (int k = 0; k < 9; k++) acc[co] += wcc[k] * p[k];
    }
  }

  int pix = y*WWI + x;
  #pragma unroll
  for (int co = 0; co < 6; co++)
    out[((size_t)(b*6) + co)*HWP + pix] = tanhf(acc[co]);
}

// ---------------- blending: fused grid-sample + weighting (all fp32) ----------------
__global__ void k_blend(const float* __restrict__ xin, const float* __restrict__ neighbors,
                        const int* __restrict__ aidx, const float* __restrict__ albedos,
                        const float* __restrict__ flows, float* __restrict__ out)
{
  int idx = blockIdx.x*blockDim.x + threadIdx.x;
  if (idx >= HWP) return;
  int xo = idx & (WWI-1);
  int yo = idx >> 9;

  float xv[9];
  #pragma unroll
  for (int i = 0; i < 9; i++) xv[i] = xin[i];

  float f0[6];
  #pragma unroll
  for (int c = 0; c < 6; c++) f0[c] = flows[(size_t)c*HWP + idx];

  const float* alb = albedos + (size_t)aidx[0]*3*HWP;
  float albp[3];
  #pragma unroll
  for (int ch = 0; ch < 3; ch++) albp[ch] = alb[(size_t)ch*HWP + idx];

  float num0 = 0.f, num1 = 0.f, num2 = 0.f;
  float wsum = 0.f;

  #pragma unroll
  for (int n = 0; n < 2; n++) {
    float dl = xv[0] - xv[(n+1)*3 + 0];
    float dv = xv[1] - xv[(n+1)*3 + 1];
    float dt = xv[2] - xv[(n+1)*3 + 2];
    bool fl = fabsf(dl) > 0.f;

    float ofx = dl*f0[0] + dv*f0[2] + dt*f0[4];
    float ofy = dl*f0[1] + dv*f0[3] + dt*f0[5];

    float gx = ((-1.f + (2.f/511.f)*(float)xo) + ofx + 1.f)*256.f - 0.5f;
    float gy = ((-1.f + (2.f/511.f)*(float)yo) + ofy + 1.f)*256.f - 0.5f;
    gx = fminf(fmaxf(gx, 0.f), 511.f);
    gy = fminf(fmaxf(gy, 0.f), 511.f);

    float x0f = floorf(gx), y0f = floorf(gy);
    float wx = gx - x0f, wy = gy - y0f;
    int x0i = (int)x0f, y0i = (int)y0f;
    int x1i = min(x0i + 1, WWI-1), y1i = min(y0i + 1, HH-1);

    float cw[4] = {(1.f-wx)*(1.f-wy), wx*(1.f-wy), (1.f-wx)*wy, wx*wy};
    int   cp[4] = {y0i*WWI + x0i, y0i*WWI + x1i, y1i*WWI + x0i, y1i*WWI + x1i};

    const float* nb = neighbors + (size_t)n*3*HWP;
    const float* Fn = flows + (size_t)(n+1)*6*HWP;

    float s0=0.f,s1=0.f,s2=0.f;
    float l0=0.f,l1=0.f,v0=0.f,v1=0.f,t0=0.f,t1=0.f;
    #pragma unroll
    for (int c = 0; c < 4; c++) {
      int p = cp[c];
      float ww = cw[c];
      float n0 = nb[p];
      float n1 = nb[HWP + p];
      float n2 = nb[2*HWP + p];
      if (fl) {
        n0 /= alb[p];
        n1 /= alb[HWP + p];
        n2 /= alb[2*HWP + p];
      }
      s0 += ww*n0; s1 += ww*n1; s2 += ww*n2;
      l0 += ww*Fn[p];             l1 += ww*Fn[HWP + p];
      v0 += ww*Fn[2*HWP + p];     v1 += ww*Fn[3*HWP + p];
      t0 += ww*Fn[4*HWP + p];     t1 += ww*Fn[5*HWP + p];
    }

    float wi0 = fl ? s0*albp[0] : s0;
    float wi1 = fl ? s1*albp[1] : s1;
    float wi2 = fl ? s2*albp[2] : s2;

    float obx = dl*l0 + dv*v0 + dt*t0;
    float oby = dl*l1 + dv*v1 + dt*t1;
    float dist = fabsf(ofx - obx) + fabsf(ofy - oby);
    float wgt = expf(-51.2f * dist);

    wsum += wgt;
    num0 += wgt*wi0; num1 += wgt*wi1; num2 += wgt*wi2;
  }

  float inv = 1.f / (wsum + 1e-5f);
  out[idx]         = num0*inv;
  out[HWP + idx]   = num1*inv;
  out[2*HWP + idx] = num2*inv;
}

// ---------------- launch ----------------
extern "C" void kernel_launch(void* const* d_in, const int* in_sizes, int n_in,
                              void* d_out, int out_size, void* d_ws, size_t ws_size,
                              hipStream_t stream) {
  const float* x         = (const float*)d_in[0];
  const float* neighbors = (const float*)d_in[1];
  const int*   aidx      = (const int*)d_in[2];
  const float* wts[10];
  const float* bis[10];
  for (int i = 0; i < 9; i++) { wts[i] = (const float*)d_in[3+2*i]; bis[i] = (const float*)d_in[4+2*i]; }
  wts[9] = (const float*)d_in[21];   // wf
  bis[9] = (const float*)d_in[22];   // bf
  const float* albedos = (const float*)d_in[23];

  float* wk   = (float*)d_ws;
  float* bufS = wk;                   // 792 floats (layer0 out)
  float* bufA = wk + 800;             // up to 4,718,592 floats
  float* bufB = bufA + 4718592;       // up to 12,582,912 floats
  size_t need = (size_t)(800 + 4718592 + 12582912) * 4;
  if (ws_size < need) return;

  // Folded-weight buffers live in bufA slack [3,200,000, 3,216,384):
  // above L7's peak use (3,145,728 floats) and only overwritten by k_final
  // (4,718,592 floats) AFTER L8 has consumed them. No workspace growth.
  float* wf6 = bufA + 3200000;            // 16*32*16 = 8192 floats
  float* wf7 = wf6 + 8192;                // 16*16*16 = 4096 floats
  float* wf8 = wf7 + 4096;                // 16*16*16 = 4096 floats
  k_foldw3<<<4, 256, 0, stream>>>(wts[6], wts[7], wts[8], wf6, wf7, wf8);

  k_layer0<<<1, 256, 0, stream>>>(x, wts[0], bis[0], bufS);

  auto spanOf = [](int Hin, int TR) { int s = TR/2 + 2; return (s > Hin) ? Hin : s; };
  auto ldsB = [&](int COB, int Cin, int Hin, int TR) {
    return (size_t)(COB*Cin*9 + COB + Cin*spanOf(Hin,TR)*Hin) * 4;
  };

  // L1: Cin=66 CO=64 Hin=2  | COB=16 TR=4 G=1 | blocks 3*4*1=12
  k_conv_lds<1><<<12, 256, ldsB(16,66,2,4), stream>>>(bufS, bufA, wts[1], bis[1],
                                                      3, 66, 64, 16, 2, 4, spanOf(2,4));
  // L2: Cin=64 CO=64 Hin=4  | COB=8 TR=8 G=1 | blocks 3*8*1=24
  k_conv_lds<1><<<24, 256, ldsB(8,64,4,8), stream>>>(bufA, bufB, wts[2], bis[2],
                                                     3, 64, 64, 8, 4, 8, spanOf(4,8));
  // L3: Cin=64 CO=32 Hin=8  | COB=4 TR=16 G=2 | blocks 3*8*1=24
  k_conv_lds<2><<<24, 256, ldsB(4,64,8,16), stream>>>(bufB, bufA, wts[3], bis[3],
                                                      3, 64, 32, 4, 8, 16, spanOf(8,16));
  // L4: Cin=32 CO=32 Hin=16 | COB=8 TR=8 G=2 | blocks 3*4*4=48
  k_conv_lds<2><<<48, 256, ldsB(8,32,16,8), stream>>>(bufA, bufB, wts[4], bis[4],
                                                      3, 32, 32, 8, 16, 8, spanOf(16,8));
  // L5: Cin=32 CO=32 Hin=32 | COB=8 TR=8 G=4 | blocks 3*4*8=96
  k_conv_lds<4><<<96, 256, ldsB(8,32,32,8), stream>>>(bufB, bufA, wts[5], bis[5],
                                                      3, 32, 32, 8, 32, 8, spanOf(32,8));

  auto blocks = [](int total){ return (total + 255) / 256; };
  // L6: small grid -> proven thread-per-output kernel
  k_upconv<16><<<blocks(3*128*128), 256, 0, stream>>>(bufA, bufB, wts[6], bis[6], 3, 32, 64);
  // L7/L8: quad decomposition, co-split x4 (acc=16 regs, cap raised to 128 VGPR)
  k_upconv_q<4><<<blocks(3*128*128*4), 256, 0, stream>>>(bufB, bufA, wf7, bis[7], 3, 16, 16, 128);
  k_upconv_q<4><<<blocks(3*256*256*4), 256, 0, stream>>>(bufA, bufB, wf8, bis[8], 3, 16, 16, 256);

  k_final<<<blocks(3*HWP), 256, 0, stream>>>(bufB, bufA, wts[9], bis[9]);
  k_blend<<<blocks(HWP), 256, 0, stream>>>(x, neighbors, aidx, albedos, bufA, (float*)d_out);
}

// Round 5
// 522.006 us; speedup vs baseline: 1.7202x; 1.2203x over previous
//
#include <hip/hip_runtime.h>
#include <hip/hip_bf16.h>
#include <math.h>

// All inputs and the output are FLOAT32 (reference dtype). The "bf16" in the
// harness label is a literal string, not a dtype indicator.
//
// R1/R3/R4 lesson: multi-output quad kernels (acc[4][*]) spill — the allocator
// pins 64 VGPR (8-wave bucket) even under __launch_bounds__(256,4), spilling
// ~12-26 floats/thread to scratch (excess WRITE_SIZE is the tell). Fix: keep
// thread-per-OUTPUT (k_upconv's proven 40-VGPR shape) and get the 2.25x FLOP
// reduction via per-output PARITY folded 2x2 weights instead of 3x3.

#define HH 512
#define WWI 512
#define HWP (HH*WWI)

// ---------------- layer 0: 1x1 conv on upsampled 2x2 + leakyrelu + coordconv ----------------
__global__ void k_layer0(const float* __restrict__ xin, const float* __restrict__ w,
                         const float* __restrict__ bias, float* __restrict__ out)
{
  for (int idx = threadIdx.x; idx < 3*66*4; idx += blockDim.x) {
    int pos = idx & 3;
    int c = (idx >> 2) % 66;
    int b = idx / (66*4);
    float v;
    if (c < 64) {
      float a = bias[c];
      #pragma unroll
      for (int ci = 0; ci < 3; ci++) a += w[c*3+ci] * xin[b*3+ci];
      v = (a >= 0.f) ? a : 0.01f*a;
    } else {
      int xx = pos & 1, yy = pos >> 1;
      v = (c == 64) ? 2.f*(float)xx : 2.f*(float)yy;
    }
    out[idx] = v;
  }
}

__device__ __forceinline__ int refl_up(int t, int n) {
  t = (t < 0) ? -t : t;
  t = (t >= n) ? (2*(n-1) - t) : t;
  return t >> 1;
}

// ---------------- LDS conv: upsample x2 + reflect-pad + 3x3 + leakyrelu ----------------
template<int G>
__global__ void k_conv_lds(const float* __restrict__ in, float* __restrict__ out,
                           const float* __restrict__ w, const float* __restrict__ bias,
                           int B, int Cin, int CO, int COB, int Hin, int TR, int SPAN)
{
  extern __shared__ float lds[];
  const int Hout = Hin * 2;
  const int rowTiles = Hout / TR;
  const int coTiles = CO / COB;
  int bid = blockIdx.x;
  int tile = bid % rowTiles;
  int cot  = (bid / rowTiles) % coTiles;
  int b    = bid / (rowTiles * coTiles);
  int tr0  = tile * TR;
  int co_base = cot * COB;

  int r0 = tr0/2 - 1;
  if (r0 < 0) r0 = 0;
  if (r0 > Hin - SPAN) r0 = Hin - SPAN;

  float* wlds = lds;                    // COB*Cin*9
  float* blds = wlds + COB*Cin*9;       // COB
  float* ilds = blds + COB;             // Cin*SPAN*Hin

  int nt = blockDim.x, tid = threadIdx.x;

  const float* wsrc = w + (size_t)co_base*Cin*9;
  for (int i = tid; i < COB*Cin*9; i += nt) wlds[i] = wsrc[i];
  for (int i = tid; i < COB; i += nt) blds[i] = bias[co_base + i];
  int icount = Cin*SPAN*Hin;
  for (int i = tid; i < icount; i += nt) {
    int col = i % Hin;
    int r = (i / Hin) % SPAN;
    int ci = i / (Hin*SPAN);
    ilds[i] = in[(((size_t)b*Cin + ci)*Hin + (r0 + r))*Hin + col];
  }
  __syncthreads();

  int npix = TR * Hout;
  int ngr = COB / G;
  int items = ngr * npix;
  for (int it = tid; it < items; it += nt) {
    int pix = it % npix;
    int cg = it / npix;
    int x = pix % Hout;
    int y = tr0 + pix / Hout;

    int ry[3], rx[3];
    #pragma unroll
    for (int d = 0; d < 3; d++) {
      int s = refl_up(y - 1 + d, Hout) - r0;
      s = (s < 0) ? 0 : s;
      s = (s > SPAN-1) ? SPAN-1 : s;
      ry[d] = s;
      rx[d] = refl_up(x - 1 + d, Hout);
    }

    float acc[G];
    #pragma unroll
    for (int j = 0; j < G; j++) acc[j] = blds[cg*G + j];

    for (int ci = 0; ci < Cin; ci++) {
      const float* ib = ilds + (size_t)ci*SPAN*Hin;
      float p[9];
      #pragma unroll
      for (int dy = 0; dy < 3; dy++)
        #pragma unroll
        for (int dx = 0; dx < 3; dx++)
          p[dy*3+dx] = ib[ry[dy]*Hin + rx[dx]];
      const float* wc = wlds + ((size_t)(cg*G)*Cin + ci)*9;
      #pragma unroll
      for (int j = 0; j < G; j++) {
        #pragma unroll
        for (int k = 0; k < 9; k++) acc[j] += wc[(size_t)j*Cin*9 + k] * p[k];
      }
    }

    #pragma unroll
    for (int j = 0; j < G; j++) {
      float v = acc[j];
      v = (v >= 0.f) ? v : 0.01f*v;
      out[(((size_t)b*CO + co_base + cg*G + j)*Hout + y)*Hout + x] = v;
    }
  }
}

// ---------------- weight folding for upsample-conv parity decomposition ----------------
// upsample x2 + reflect-pad + 3x3 VALID conv == per-output-parity 2x2 conv on the
// ORIGINAL (pre-upsample) image:
//   even y (py=0): rows (Y-1, Y), weights (w0, w1+w2); odd y: rows (Y, Y+1), (w0+w1, w2).
//   Same in x. Border reflection == clamping the outer source row/col (verified vs refl_up:
//   folded weights collapse onto the same row, total w0+w1+w2, matching reference).
// Folded layout: f[((co*Cin + ci)*16) + p*4 + ky*2 + kx], p = py*2+px. 16B-aligned float4 per p.
__global__ void k_foldw3(const float* __restrict__ w6, const float* __restrict__ w7,
                         const float* __restrict__ w8, float* __restrict__ f6,
                         float* __restrict__ f7, float* __restrict__ f8)
{
  int idx = blockIdx.x*blockDim.x + threadIdx.x;
  const float* w; float* f; int n;
  if (idx < 512)       { w = w6; f = f6; n = idx; }        // CO=16, Cin=32
  else if (idx < 768)  { w = w7; f = f7; n = idx - 512; }  // CO=16, Cin=16
  else if (idx < 1024) { w = w8; f = f8; n = idx - 768; }  // CO=16, Cin=16
  else return;

  const float* ws = w + (size_t)n*9;
  float W[9];
  #pragma unroll
  for (int k = 0; k < 9; k++) W[k] = ws[k];

  // row folds a[py][ky][c]
  float a[2][2][3];
  #pragma unroll
  for (int c = 0; c < 3; c++) {
    a[0][0][c] = W[c];          a[0][1][c] = W[3+c] + W[6+c];
    a[1][0][c] = W[c] + W[3+c]; a[1][1][c] = W[6+c];
  }
  float* fo = f + (size_t)n*16;
  #pragma unroll
  for (int py = 0; py < 2; py++)
    #pragma unroll
    for (int px = 0; px < 2; px++) {
      int p = py*2 + px;
      #pragma unroll
      for (int ky = 0; ky < 2; ky++) {
        float kx0 = (px == 0) ? a[py][ky][0] : (a[py][ky][0] + a[py][ky][1]);
        float kx1 = (px == 0) ? (a[py][ky][1] + a[py][ky][2]) : a[py][ky][2];
        fo[p*4 + ky*2 + 0] = kx0;
        fo[p*4 + ky*2 + 1] = kx1;
      }
    }
}

// ---------------- parity upconv: one thread per OUTPUT pixel, folded 2x2 weights ----------
// Same proven shape as k_upconv (acc[CO]=16 regs, no spill) but 4 pixel loads + 1024 FMAs
// per output instead of 9 + 2304. Within a wave only px alternates -> weight float4 loads
// hit 2 distinct 16B lines (broadcast-class); pixel loads & stores stay coalesced.
template<int CO>
__global__ void k_upconv_p(const float* __restrict__ in, float* __restrict__ out,
                           const float* __restrict__ wfold, const float* __restrict__ bias,
                           int B, int Cin, int Hin)
{
  int Hout = Hin * 2;
  int total = B * Hout * Hout;
  int idx = blockIdx.x*blockDim.x + threadIdx.x;
  if (idx >= total) return;
  int x = idx % Hout;
  int y = (idx / Hout) % Hout;
  int b = idx / (Hout * Hout);

  int X = x >> 1, Y = y >> 1;
  int px = x & 1, py = y & 1;
  int p = py*2 + px;

  // folded source rows/cols (reflection == clamp at borders)
  int r_lo = py ? Y : (Y > 0 ? Y-1 : 0);
  int r_hi = py ? (Y < Hin-1 ? Y+1 : Hin-1) : Y;
  int c_lo = px ? X : (X > 0 ? X-1 : 0);
  int c_hi = px ? (X < Hin-1 ? X+1 : Hin-1) : X;

  float acc[CO];
  #pragma unroll
  for (int co = 0; co < CO; co++) acc[co] = bias[co];

  const size_t plane = (size_t)Hin * Hin;
  const float* ibase = in + (size_t)b * Cin * plane;
  const float* wbase = wfold + (size_t)p * 4;   // + (co*Cin + ci)*16
  for (int ci = 0; ci < Cin; ci++) {
    const float* ip = ibase + (size_t)ci * plane;
    const float* rl = ip + (size_t)r_lo * Hin;
    const float* rh = ip + (size_t)r_hi * Hin;
    float p00 = rl[c_lo], p01 = rl[c_hi];
    float p10 = rh[c_lo], p11 = rh[c_hi];

    const float* wc = wbase + (size_t)ci * 16;
    #pragma unroll
    for (int co = 0; co < CO; co++) {
      float4 w4 = *reinterpret_cast<const float4*>(wc + (size_t)co * Cin * 16);
      acc[co] += w4.x*p00 + w4.y*p01 + w4.z*p10 + w4.w*p11;
    }
  }

  int pix = y*Hout + x;
  #pragma unroll
  for (int co = 0; co < CO; co++) {
    float v = acc[co];
    v = (v >= 0.f) ? v : 0.01f*v;
    out[((size_t)b*CO + co)*((size_t)Hout*Hout) + pix] = v;
  }
}

// ---------------- final: reflect-pad + 3x3 conv (16 -> 6) + tanh ----------------
__global__ void k_final(const float* __restrict__ in, float* __restrict__ out,
                        const float* __restrict__ w, const float* __restrict__ bias)
{
  int idx = blockIdx.x*blockDim.x + threadIdx.x;
  int total = 3 * HWP;
  if (idx >= total) return;
  int x = idx & (WWI-1);
  int y = (idx >> 9) & (HH-1);
  int b = idx / HWP;

  int ry[3], rx[3];
  #pragma unroll
  for (int d = 0; d < 3; d++) {
    int t = y - 1 + d;
    t = (t < 0) ? -t : t;
    ry[d] = (t >= HH) ? (2*(HH-1) - t) : t;
    t = x - 1 + d;
    t = (t < 0) ? -t : t;
    rx[d] = (t >= WWI) ? (2*(WWI-1) - t) : t;
  }

  float acc[6];
  #pragma unroll
  for (int co = 0; co < 6; co++) acc[co] = bias[co];

  for (int ci = 0; ci < 16; ci++) {
    const float* ib = in + ((size_t)(b*16) + ci) * HWP;
    float p[9];
    #pragma unroll
    for (int dy = 0; dy < 3; dy++)
      #pragma unroll
      for (int dx = 0; dx < 3; dx++)
        p[dy*3+dx] = ib[ry[dy]*WWI + rx[dx]];
    const float* wc = w + ci*9;
    #pragma unroll
    for (int co = 0; co < 6; co++) {
      const float* wcc = wc + co*16*9;
      #pragma unroll
      for (int k = 0; k < 9; k++) acc[co] += wcc[k] * p[k];
    }
  }

  int pix = y*WWI + x;
  #pragma unroll
  for (int co = 0; co < 6; co++)
    out[((size_t)(b*6) + co)*HWP + pix] = tanhf(acc[co]);
}

// ---------------- blending: fused grid-sample + weighting (all fp32) ----------------
__global__ void k_blend(const float* __restrict__ xin, const float* __restrict__ neighbors,
                        const int* __restrict__ aidx, const float* __restrict__ albedos,
                        const float* __restrict__ flows, float* __restrict__ out)
{
  int idx = blockIdx.x*blockDim.x + threadIdx.x;
  if (idx >= HWP) return;
  int xo = idx & (WWI-1);
  int yo = idx >> 9;

  float xv[9];
  #pragma unroll
  for (int i = 0; i < 9; i++) xv[i] = xin[i];

  float f0[6];
  #pragma unroll
  for (int c = 0; c < 6; c++) f0[c] = flows[(size_t)c*HWP + idx];

  const float* alb = albedos + (size_t)aidx[0]*3*HWP;
  float albp[3];
  #pragma unroll
  for (int ch = 0; ch < 3; ch++) albp[ch] = alb[(size_t)ch*HWP + idx];

  float num0 = 0.f, num1 = 0.f, num2 = 0.f;
  float wsum = 0.f;

  #pragma unroll
  for (int n = 0; n < 2; n++) {
    float dl = xv[0] - xv[(n+1)*3 + 0];
    float dv = xv[1] - xv[(n+1)*3 + 1];
    float dt = xv[2] - xv[(n+1)*3 + 2];
    bool fl = fabsf(dl) > 0.f;

    float ofx = dl*f0[0] + dv*f0[2] + dt*f0[4];
    float ofy = dl*f0[1] + dv*f0[3] + dt*f0[5];

    float gx = ((-1.f + (2.f/511.f)*(float)xo) + ofx + 1.f)*256.f - 0.5f;
    float gy = ((-1.f + (2.f/511.f)*(float)yo) + ofy + 1.f)*256.f - 0.5f;
    gx = fminf(fmaxf(gx, 0.f), 511.f);
    gy = fminf(fmaxf(gy, 0.f), 511.f);

    float x0f = floorf(gx), y0f = floorf(gy);
    float wx = gx - x0f, wy = gy - y0f;
    int x0i = (int)x0f, y0i = (int)y0f;
    int x1i = min(x0i + 1, WWI-1), y1i = min(y0i + 1, HH-1);

    float cw[4] = {(1.f-wx)*(1.f-wy), wx*(1.f-wy), (1.f-wx)*wy, wx*wy};
    int   cp[4] = {y0i*WWI + x0i, y0i*WWI + x1i, y1i*WWI + x0i, y1i*WWI + x1i};

    const float* nb = neighbors + (size_t)n*3*HWP;
    const float* Fn = flows + (size_t)(n+1)*6*HWP;

    float s0=0.f,s1=0.f,s2=0.f;
    float l0=0.f,l1=0.f,v0=0.f,v1=0.f,t0=0.f,t1=0.f;
    #pragma unroll
    for (int c = 0; c < 4; c++) {
      int p = cp[c];
      float ww = cw[c];
      float n0 = nb[p];
      float n1 = nb[HWP + p];
      float n2 = nb[2*HWP + p];
      if (fl) {
        n0 /= alb[p];
        n1 /= alb[HWP + p];
        n2 /= alb[2*HWP + p];
      }
      s0 += ww*n0; s1 += ww*n1; s2 += ww*n2;
      l0 += ww*Fn[p];             l1 += ww*Fn[HWP + p];
      v0 += ww*Fn[2*HWP + p];     v1 += ww*Fn[3*HWP + p];
      t0 += ww*Fn[4*HWP + p];     t1 += ww*Fn[5*HWP + p];
    }

    float wi0 = fl ? s0*albp[0] : s0;
    float wi1 = fl ? s1*albp[1] : s1;
    float wi2 = fl ? s2*albp[2] : s2;

    float obx = dl*l0 + dv*v0 + dt*t0;
    float oby = dl*l1 + dv*v1 + dt*t1;
    float dist = fabsf(ofx - obx) + fabsf(ofy - oby);
    float wgt = expf(-51.2f * dist);

    wsum += wgt;
    num0 += wgt*wi0; num1 += wgt*wi1; num2 += wgt*wi2;
  }

  float inv = 1.f / (wsum + 1e-5f);
  out[idx]         = num0*inv;
  out[HWP + idx]   = num1*inv;
  out[2*HWP + idx] = num2*inv;
}

// ---------------- launch ----------------
extern "C" void kernel_launch(void* const* d_in, const int* in_sizes, int n_in,
                              void* d_out, int out_size, void* d_ws, size_t ws_size,
                              hipStream_t stream) {
  const float* x         = (const float*)d_in[0];
  const float* neighbors = (const float*)d_in[1];
  const int*   aidx      = (const int*)d_in[2];
  const float* wts[10];
  const float* bis[10];
  for (int i = 0; i < 9; i++) { wts[i] = (const float*)d_in[3+2*i]; bis[i] = (const float*)d_in[4+2*i]; }
  wts[9] = (const float*)d_in[21];   // wf
  bis[9] = (const float*)d_in[22];   // bf
  const float* albedos = (const float*)d_in[23];

  float* wk   = (float*)d_ws;
  float* bufS = wk;                   // 792 floats (layer0 out)
  float* bufA = wk + 800;             // up to 4,718,592 floats
  float* bufB = bufA + 4718592;       // up to 12,582,912 floats
  size_t need = (size_t)(800 + 4718592 + 12582912) * 4;
  if (ws_size < need) return;

  // Folded-weight buffers live in bufA slack [3,200,000, 3,216,384):
  // above L7's peak use (3,145,728 floats) and only overwritten by k_final
  // (4,718,592 floats) AFTER L8 has consumed them. No workspace growth.
  float* wf6 = bufA + 3200000;            // 16*32*16 = 8192 floats
  float* wf7 = wf6 + 8192;                // 16*16*16 = 4096 floats
  float* wf8 = wf7 + 4096;                // 16*16*16 = 4096 floats
  k_foldw3<<<4, 256, 0, stream>>>(wts[6], wts[7], wts[8], wf6, wf7, wf8);

  k_layer0<<<1, 256, 0, stream>>>(x, wts[0], bis[0], bufS);

  auto spanOf = [](int Hin, int TR) { int s = TR/2 + 2; return (s > Hin) ? Hin : s; };
  auto ldsB = [&](int COB, int Cin, int Hin, int TR) {
    return (size_t)(COB*Cin*9 + COB + Cin*spanOf(Hin,TR)*Hin) * 4;
  };

  // L1: Cin=66 CO=64 Hin=2  | COB=16 TR=4 G=1 | blocks 3*4*1=12
  k_conv_lds<1><<<12, 256, ldsB(16,66,2,4), stream>>>(bufS, bufA, wts[1], bis[1],
                                                      3, 66, 64, 16, 2, 4, spanOf(2,4));
  // L2: Cin=64 CO=64 Hin=4  | COB=8 TR=8 G=1 | blocks 3*8*1=24
  k_conv_lds<1><<<24, 256, ldsB(8,64,4,8), stream>>>(bufA, bufB, wts[2], bis[2],
                                                     3, 64, 64, 8, 4, 8, spanOf(4,8));
  // L3: Cin=64 CO=32 Hin=8  | COB=4 TR=16 G=2 | blocks 3*8*1=24
  k_conv_lds<2><<<24, 256, ldsB(4,64,8,16), stream>>>(bufB, bufA, wts[3], bis[3],
                                                      3, 64, 32, 4, 8, 16, spanOf(8,16));
  // L4: Cin=32 CO=32 Hin=16 | COB=8 TR=8 G=2 | blocks 3*4*4=48
  k_conv_lds<2><<<48, 256, ldsB(8,32,16,8), stream>>>(bufA, bufB, wts[4], bis[4],
                                                      3, 32, 32, 8, 16, 8, spanOf(16,8));
  // L5: Cin=32 CO=32 Hin=32 | COB=8 TR=8 G=4 | blocks 3*4*8=96
  k_conv_lds<4><<<96, 256, ldsB(8,32,32,8), stream>>>(bufB, bufA, wts[5], bis[5],
                                                      3, 32, 32, 8, 32, 8, spanOf(32,8));

  auto blocks = [](int total){ return (total + 255) / 256; };
  // L6-L8: parity-folded upconv (thread-per-output, acc[16], no spill risk)
  k_upconv_p<16><<<blocks(3*128*128), 256, 0, stream>>>(bufA, bufB, wf6, bis[6], 3, 32, 64);
  k_upconv_p<16><<<blocks(3*256*256), 256, 0, stream>>>(bufB, bufA, wf7, bis[7], 3, 16, 128);
  k_upconv_p<16><<<blocks(3*512*512), 256, 0, stream>>>(bufA, bufB, wf8, bis[8], 3, 16, 256);

  k_final<<<blocks(3*HWP), 256, 0, stream>>>(bufB, bufA, wts[9], bis[9]);
  k_blend<<<blocks(HWP), 256, 0, stream>>>(x, neighbors, aidx, albedos, bufA, (float*)d_out);
}